// Round 6
// baseline (2604.172 us; speedup 1.0000x reference)
//
#include <hip/hip_runtime.h>
#include <hip/hip_bf16.h>

#define LEAKY(v) ((v) >= 0.0f ? (v) : 0.01f * (v))

typedef int iv4 __attribute__((ext_vector_type(4)));

// ---------------------------------------------------------------------------
// k_init: ego -> out cols [0,64) (raw; also serves as layer-0 input).
// ---------------------------------------------------------------------------
__global__ void k_init(const float* __restrict__ ego, float* __restrict__ out, int n) {
  int tid = blockIdx.x * blockDim.x + threadIdx.x;
  int total = n * 16;
  int stride = gridDim.x * blockDim.x;
  for (int t = tid; t < total; t += stride) {
    int r = t >> 4, c = (t & 15) * 4;
    float4 v = *(const float4*)(ego + (size_t)r * 64 + c);
    *(float4*)(out + (size_t)r * 176 + c) = v;
  }
}

// ---------------------------------------------------------------------------
// CSR build: histogram -> single-block scan -> scatter (col,val as int2)
// ---------------------------------------------------------------------------
__global__ void k_count(const int* __restrict__ erow, int* __restrict__ cnt, int E) {
  int tid = blockIdx.x * blockDim.x + threadIdx.x;
  int stride = gridDim.x * blockDim.x;
  for (int e = tid; e < E; e += stride) atomicAdd(&cnt[erow[e]], 1);
}

__global__ void __launch_bounds__(1024) k_scan(const int* __restrict__ cnt,
                                               int* __restrict__ rp, int n) {
  __shared__ int ssum[1024];
  int t = threadIdx.x;
  int chunk = (n + 1023) >> 10;
  int beg = t * chunk;
  int end = min(beg + chunk, n);
  int s = 0;
  for (int i = beg; i < end; ++i) s += cnt[i];
  ssum[t] = s;
  __syncthreads();
  for (int off = 1; off < 1024; off <<= 1) {
    int v = (t >= off) ? ssum[t - off] : 0;
    __syncthreads();
    ssum[t] += v;
    __syncthreads();
  }
  int excl = (t == 0) ? 0 : ssum[t - 1];
  for (int i = beg; i < end; ++i) {
    rp[i] = excl;
    excl += cnt[i];
  }
  if (t == 1023) rp[n] = excl;
}

__global__ void k_scatter(const int* __restrict__ erow, const int* __restrict__ ecol,
                          const float* __restrict__ ev, int* cur,
                          int2* __restrict__ cv, int E) {
  int tid = blockIdx.x * blockDim.x + threadIdx.x;
  int stride = gridDim.x * blockDim.x;
  for (int e = tid; e < E; e += stride) {
    int r = erow[e];
    int pos = atomicAdd(&cur[r], 1);
    int2 p;
    p.x = ecol[e];
    p.y = __float_as_int(ev[e]);
    cv[pos] = p;
  }
}

// ---------------------------------------------------------------------------
// k_layer: fused SpMM (CSR gather, 8-wide MLP) + transform.
// One wave per row; lane = feature (f = lane & (DIN-1)).
//   side = sum val_e * xin[col_e]  (registers)
//   xn = leaky((x+side)@W1+b1) + leaky((x*side)@W2+b2)  -> outp (UNnormalized)
// xin = out + col0_in (stride 176), outp = out + col0_out: same buffer,
// disjoint column ranges -> no __restrict__ on either.
// ---------------------------------------------------------------------------
template <int DIN, int DOUT>
__global__ void __launch_bounds__(256) k_layer(
    const int* __restrict__ rp, const int2* __restrict__ cv,
    const float* xin,
    const float* __restrict__ W1, const float* __restrict__ b1,
    const float* __restrict__ W2, const float* __restrict__ b2,
    float* outp, int n) {
  __shared__ float sW1[DIN * DOUT + 64];
  __shared__ float sW2[DIN * DOUT + 64];
  __shared__ float sb[128];
  for (int i = threadIdx.x; i < DIN * DOUT + 64; i += blockDim.x) {
    sW1[i] = (i < DIN * DOUT) ? W1[i] : 0.0f;
    sW2[i] = (i < DIN * DOUT) ? W2[i] : 0.0f;
  }
  if (threadIdx.x < 64) {
    int i = threadIdx.x;
    sb[i] = (i < DOUT) ? b1[i] : 0.0f;
    sb[64 + i] = (i < DOUT) ? b2[i] : 0.0f;
  }
  __syncthreads();

  int row = (int)((blockIdx.x * (unsigned)blockDim.x + threadIdx.x) >> 6);
  int lane = threadIdx.x & 63;
  if (row >= n) return;

  int f = lane & (DIN - 1);
  int beg = rp[row], end = rp[row + 1];
  float acc = 0.0f;
  int e = beg;

  // scalar head: align e to even so int4 loads of cv are 16B-aligned
  if ((e & 1) && e < end) {
    int2 q = cv[e];
    acc = fmaf(__int_as_float(q.y), xin[(size_t)q.x * 176 + f], acc);
    ++e;
  }
  // 8-wide body: 4 independent nt int4 loads (8 edges) + 8 independent gathers
  for (; e + 8 <= end; e += 8) {
    iv4 a = __builtin_nontemporal_load((const iv4*)(cv + e));
    iv4 b = __builtin_nontemporal_load((const iv4*)(cv + e + 2));
    iv4 c = __builtin_nontemporal_load((const iv4*)(cv + e + 4));
    iv4 d = __builtin_nontemporal_load((const iv4*)(cv + e + 6));
    float g0 = xin[(size_t)a.x * 176 + f];
    float g1 = xin[(size_t)a.z * 176 + f];
    float g2 = xin[(size_t)b.x * 176 + f];
    float g3 = xin[(size_t)b.z * 176 + f];
    float g4 = xin[(size_t)c.x * 176 + f];
    float g5 = xin[(size_t)c.z * 176 + f];
    float g6 = xin[(size_t)d.x * 176 + f];
    float g7 = xin[(size_t)d.z * 176 + f];
    acc = fmaf(__int_as_float(a.y), g0, acc);
    acc = fmaf(__int_as_float(a.w), g1, acc);
    acc = fmaf(__int_as_float(b.y), g2, acc);
    acc = fmaf(__int_as_float(b.w), g3, acc);
    acc = fmaf(__int_as_float(c.y), g4, acc);
    acc = fmaf(__int_as_float(c.w), g5, acc);
    acc = fmaf(__int_as_float(d.y), g6, acc);
    acc = fmaf(__int_as_float(d.w), g7, acc);
  }
  // pair tail
  for (; e + 2 <= end; e += 2) {
    iv4 a = __builtin_nontemporal_load((const iv4*)(cv + e));
    float g0 = xin[(size_t)a.x * 176 + f];
    float g1 = xin[(size_t)a.z * 176 + f];
    acc = fmaf(__int_as_float(a.y), g0, acc);
    acc = fmaf(__int_as_float(a.w), g1, acc);
  }
  // scalar tail
  if (e < end) {
    int2 q = cv[e];
    acc = fmaf(__int_as_float(q.y), xin[(size_t)q.x * 176 + f], acc);
  }

  float xv = (lane < DIN) ? xin[(size_t)row * 176 + lane] : 0.0f;
  float a_ = xv + acc;
  float m_ = xv * acc;

  float acc1 = sb[lane], acc2 = sb[64 + lane];
#pragma unroll
  for (int k = 0; k < DIN; ++k) {
    float ak = __shfl(a_, k), mk = __shfl(m_, k);
    acc1 = fmaf(ak, sW1[k * DOUT + lane], acc1);
    acc2 = fmaf(mk, sW2[k * DOUT + lane], acc2);
  }
  float xn = LEAKY(acc1) + LEAKY(acc2);
  if (lane < DOUT) outp[(size_t)row * 176 + lane] = xn;
}

// ---------------------------------------------------------------------------
// k_norm: final pass, L2-normalize cols [64,128), [128,160), [160,176)
// in place. One wave per row.
// ---------------------------------------------------------------------------
__global__ void __launch_bounds__(256) k_norm(float* out, int n) {
  int row = (int)((blockIdx.x * (unsigned)blockDim.x + threadIdx.x) >> 6);
  int lane = threadIdx.x & 63;
  if (row >= n) return;
  float* r = out + (size_t)row * 176;
  float a = r[64 + lane];
  float b = (lane < 48) ? r[128 + lane] : 0.0f;
  float sa = a * a;
  float sb_ = (lane < 32) ? b * b : 0.0f;
  float sc = (lane >= 32 && lane < 48) ? b * b : 0.0f;
#pragma unroll
  for (int off = 32; off; off >>= 1) {
    sa += __shfl_xor(sa, off);
    sb_ += __shfl_xor(sb_, off);
    sc += __shfl_xor(sc, off);
  }
  float ia = 1.0f / fmaxf(sqrtf(sa), 1e-12f);
  float ib = 1.0f / fmaxf(sqrtf(sb_), 1e-12f);
  float ic = 1.0f / fmaxf(sqrtf(sc), 1e-12f);
  r[64 + lane] = a * ia;
  if (lane < 48) r[128 + lane] = b * ((lane < 32) ? ib : ic);
}

// ---------------------------------------------------------------------------
extern "C" void kernel_launch(void* const* d_in, const int* in_sizes, int n_in,
                              void* d_out, int out_size, void* d_ws, size_t ws_size,
                              hipStream_t stream) {
  const float* ego = (const float*)d_in[0];
  const int* erow = (const int*)d_in[1];
  const int* ecol = (const int*)d_in[2];
  const float* ev = (const float*)d_in[3];
  const int n = in_sizes[0] / 64;  // 160000
  const int E = in_sizes[1];       // 5120000

  float* out = (float*)d_out;  // [n, 176] f32

  // ws layout: cv[E] | rp[n+1] | cnt[n] | cur[n]   (~43 MB, proven budget)
  int2* cv = (int2*)d_ws;
  int* rp = (int*)(cv + E);
  int* cnt = rp + n + 1;
  int* cur = cnt + n;

  const int rblocks = (n + 3) / 4;  // one wave per row, 4 waves/block

  k_init<<<2048, 256, 0, stream>>>(ego, out, n);
  hipMemsetAsync(cnt, 0, (size_t)n * sizeof(int), stream);
  k_count<<<2048, 256, 0, stream>>>(erow, cnt, E);
  k_scan<<<1, 1024, 0, stream>>>(cnt, rp, n);
  hipMemcpyAsync(cur, rp, (size_t)n * sizeof(int), hipMemcpyDeviceToDevice, stream);
  k_scatter<<<2048, 256, 0, stream>>>(erow, ecol, ev, cur, cv, E);

  k_layer<64, 64><<<rblocks, 256, 0, stream>>>(
      rp, cv, out, (const float*)d_in[4], (const float*)d_in[5],
      (const float*)d_in[6], (const float*)d_in[7], out + 64, n);
  k_layer<64, 32><<<rblocks, 256, 0, stream>>>(
      rp, cv, out + 64, (const float*)d_in[8], (const float*)d_in[9],
      (const float*)d_in[10], (const float*)d_in[11], out + 128, n);
  k_layer<32, 16><<<rblocks, 256, 0, stream>>>(
      rp, cv, out + 128, (const float*)d_in[12], (const float*)d_in[13],
      (const float*)d_in[14], (const float*)d_in[15], out + 160, n);

  k_norm<<<rblocks, 256, 0, stream>>>(out, n);
}

// Round 7
// 1862.117 us; speedup vs baseline: 1.3985x; 1.3985x over previous
//
#include <hip/hip_runtime.h>
#include <hip/hip_bf16.h>

#define LEAKY(v) ((v) >= 0.0f ? (v) : 0.01f * (v))

typedef int iv4 __attribute__((ext_vector_type(4)));

// ---------------------------------------------------------------------------
// k_init: ego -> out cols [0,64) (raw; also serves as layer-0 input).
// ---------------------------------------------------------------------------
__global__ void k_init(const float* __restrict__ ego, float* __restrict__ out, int n) {
  int tid = blockIdx.x * blockDim.x + threadIdx.x;
  int total = n * 16;
  int stride = gridDim.x * blockDim.x;
  for (int t = tid; t < total; t += stride) {
    int r = t >> 4, c = (t & 15) * 4;
    float4 v = *(const float4*)(ego + (size_t)r * 64 + c);
    *(float4*)(out + (size_t)r * 176 + c) = v;
  }
}

// ---------------------------------------------------------------------------
// CSR build: histogram -> single-block scan -> scatter (col,val as int2)
// ---------------------------------------------------------------------------
__global__ void k_count(const int* __restrict__ erow, int* __restrict__ cnt, int E) {
  int tid = blockIdx.x * blockDim.x + threadIdx.x;
  int stride = gridDim.x * blockDim.x;
  for (int e = tid; e < E; e += stride) atomicAdd(&cnt[erow[e]], 1);
}

__global__ void __launch_bounds__(1024) k_scan(const int* __restrict__ cnt,
                                               int* __restrict__ rp, int n) {
  __shared__ int ssum[1024];
  int t = threadIdx.x;
  int chunk = (n + 1023) >> 10;
  int beg = t * chunk;
  int end = min(beg + chunk, n);
  int s = 0;
  for (int i = beg; i < end; ++i) s += cnt[i];
  ssum[t] = s;
  __syncthreads();
  for (int off = 1; off < 1024; off <<= 1) {
    int v = (t >= off) ? ssum[t - off] : 0;
    __syncthreads();
    ssum[t] += v;
    __syncthreads();
  }
  int excl = (t == 0) ? 0 : ssum[t - 1];
  for (int i = beg; i < end; ++i) {
    rp[i] = excl;
    excl += cnt[i];
  }
  if (t == 1023) rp[n] = excl;
}

__global__ void k_scatter(const int* __restrict__ erow, const int* __restrict__ ecol,
                          const float* __restrict__ ev, int* cur,
                          int2* __restrict__ cv, int E) {
  int tid = blockIdx.x * blockDim.x + threadIdx.x;
  int stride = gridDim.x * blockDim.x;
  for (int e = tid; e < E; e += stride) {
    int r = erow[e];
    int pos = atomicAdd(&cur[r], 1);
    int2 p;
    p.x = ecol[e];
    p.y = __float_as_int(ev[e]);
    cv[pos] = p;
  }
}

// ---------------------------------------------------------------------------
// k_layer: fused SpMM (CSR gather) + transform. One wave per row.
// Occupancy package: launch_bounds(256,8) -> 64-VGPR cap (32 waves/CU);
// W1/W2 packed as bf16 pair in ONE u32 LDS word (halves LDS + LDS reads).
//   side = sum val_e * xin[col_e]  (registers, lane = feature)
//   xn = leaky((x+side)@W1+b1) + leaky((x*side)@W2+b2)  -> outp (UNnormalized)
// xin/outp alias out (disjoint column ranges) -> no __restrict__.
// ---------------------------------------------------------------------------
template <int DIN, int DOUT>
__global__ void __launch_bounds__(256, 8) k_layer(
    const int* __restrict__ rp, const int2* __restrict__ cv,
    const float* xin,
    const float* __restrict__ W1, const float* __restrict__ b1,
    const float* __restrict__ W2, const float* __restrict__ b2,
    float* outp, int n) {
  __shared__ unsigned sWp[DIN * DOUT + 64];  // lo16 = bf16(W1), hi16 = bf16(W2)
  __shared__ float sb[128];
  for (int i = threadIdx.x; i < DIN * DOUT + 64; i += blockDim.x) {
    float w1 = (i < DIN * DOUT) ? W1[i] : 0.0f;
    float w2 = (i < DIN * DOUT) ? W2[i] : 0.0f;
    unsigned u1 = __float_as_uint(w1), u2 = __float_as_uint(w2);
    unsigned r1 = (u1 + 0x7fffu + ((u1 >> 16) & 1u)) >> 16;          // RNE bf16, low
    unsigned r2 = (u2 + 0x7fffu + ((u2 >> 16) & 1u)) & 0xffff0000u;  // RNE bf16, high
    sWp[i] = r1 | r2;
  }
  if (threadIdx.x < 64) {
    int i = threadIdx.x;
    sb[i] = (i < DOUT) ? b1[i] : 0.0f;
    sb[64 + i] = (i < DOUT) ? b2[i] : 0.0f;
  }
  __syncthreads();

  int row = (int)((blockIdx.x * (unsigned)blockDim.x + threadIdx.x) >> 6);
  int lane = threadIdx.x & 63;
  if (row >= n) return;

  int f = lane & (DIN - 1);
  int beg = rp[row], end = rp[row + 1];

  // independent row-x load issued before the gather loop
  float xv = (lane < DIN) ? xin[(size_t)row * 176 + lane] : 0.0f;

  float acc = 0.0f;
  int e = beg;
  // scalar head: align e to even so int4 loads of cv are 16B-aligned
  if ((e & 1) && e < end) {
    int2 q = cv[e];
    acc = fmaf(__int_as_float(q.y), xin[(size_t)q.x * 176 + f], acc);
    ++e;
  }
  // 4-wide body: 2 int4 loads (4 edges) + 4 independent gathers
  for (; e + 4 <= end; e += 4) {
    iv4 a = *(const iv4*)(cv + e);
    iv4 b = *(const iv4*)(cv + e + 2);
    float g0 = xin[(size_t)a.x * 176 + f];
    float g1 = xin[(size_t)a.z * 176 + f];
    float g2 = xin[(size_t)b.x * 176 + f];
    float g3 = xin[(size_t)b.z * 176 + f];
    acc = fmaf(__int_as_float(a.y), g0, acc);
    acc = fmaf(__int_as_float(a.w), g1, acc);
    acc = fmaf(__int_as_float(b.y), g2, acc);
    acc = fmaf(__int_as_float(b.w), g3, acc);
  }
  // pair tail
  for (; e + 2 <= end; e += 2) {
    iv4 a = *(const iv4*)(cv + e);
    float g0 = xin[(size_t)a.x * 176 + f];
    float g1 = xin[(size_t)a.z * 176 + f];
    acc = fmaf(__int_as_float(a.y), g0, acc);
    acc = fmaf(__int_as_float(a.w), g1, acc);
  }
  // scalar tail
  if (e < end) {
    int2 q = cv[e];
    acc = fmaf(__int_as_float(q.y), xin[(size_t)q.x * 176 + f], acc);
  }

  float a_ = xv + acc;
  float m_ = xv * acc;

  float acc1 = sb[lane], acc2 = sb[64 + lane];
#pragma unroll 8
  for (int k = 0; k < DIN; ++k) {
    float ak = __shfl(a_, k), mk = __shfl(m_, k);
    unsigned w = sWp[k * DOUT + lane];
    acc1 = fmaf(ak, __uint_as_float(w << 16), acc1);
    acc2 = fmaf(mk, __uint_as_float(w & 0xffff0000u), acc2);
  }
  float xn = LEAKY(acc1) + LEAKY(acc2);
  if (lane < DOUT) outp[(size_t)row * 176 + lane] = xn;
}

// ---------------------------------------------------------------------------
// k_norm: final pass, L2-normalize cols [64,128), [128,160), [160,176)
// in place. One wave per row.
// ---------------------------------------------------------------------------
__global__ void __launch_bounds__(256) k_norm(float* out, int n) {
  int row = (int)((blockIdx.x * (unsigned)blockDim.x + threadIdx.x) >> 6);
  int lane = threadIdx.x & 63;
  if (row >= n) return;
  float* r = out + (size_t)row * 176;
  float a = r[64 + lane];
  float b = (lane < 48) ? r[128 + lane] : 0.0f;
  float sa = a * a;
  float sb_ = (lane < 32) ? b * b : 0.0f;
  float sc = (lane >= 32 && lane < 48) ? b * b : 0.0f;
#pragma unroll
  for (int off = 32; off; off >>= 1) {
    sa += __shfl_xor(sa, off);
    sb_ += __shfl_xor(sb_, off);
    sc += __shfl_xor(sc, off);
  }
  float ia = 1.0f / fmaxf(sqrtf(sa), 1e-12f);
  float ib = 1.0f / fmaxf(sqrtf(sb_), 1e-12f);
  float ic = 1.0f / fmaxf(sqrtf(sc), 1e-12f);
  r[64 + lane] = a * ia;
  if (lane < 48) r[128 + lane] = b * ((lane < 32) ? ib : ic);
}

// ---------------------------------------------------------------------------
extern "C" void kernel_launch(void* const* d_in, const int* in_sizes, int n_in,
                              void* d_out, int out_size, void* d_ws, size_t ws_size,
                              hipStream_t stream) {
  const float* ego = (const float*)d_in[0];
  const int* erow = (const int*)d_in[1];
  const int* ecol = (const int*)d_in[2];
  const float* ev = (const float*)d_in[3];
  const int n = in_sizes[0] / 64;  // 160000
  const int E = in_sizes[1];       // 5120000

  float* out = (float*)d_out;  // [n, 176] f32

  // ws layout: cv[E] | rp[n+1] | cnt[n] | cur[n]   (~43 MB, proven budget)
  int2* cv = (int2*)d_ws;
  int* rp = (int*)(cv + E);
  int* cnt = rp + n + 1;
  int* cur = cnt + n;

  const int rblocks = (n + 3) / 4;  // one wave per row, 4 waves/block

  k_init<<<2048, 256, 0, stream>>>(ego, out, n);
  hipMemsetAsync(cnt, 0, (size_t)n * sizeof(int), stream);
  k_count<<<2048, 256, 0, stream>>>(erow, cnt, E);
  k_scan<<<1, 1024, 0, stream>>>(cnt, rp, n);
  hipMemcpyAsync(cur, rp, (size_t)n * sizeof(int), hipMemcpyDeviceToDevice, stream);
  k_scatter<<<2048, 256, 0, stream>>>(erow, ecol, ev, cur, cv, E);

  k_layer<64, 64><<<rblocks, 256, 0, stream>>>(
      rp, cv, out, (const float*)d_in[4], (const float*)d_in[5],
      (const float*)d_in[6], (const float*)d_in[7], out + 64, n);
  k_layer<64, 32><<<rblocks, 256, 0, stream>>>(
      rp, cv, out + 64, (const float*)d_in[8], (const float*)d_in[9],
      (const float*)d_in[10], (const float*)d_in[11], out + 128, n);
  k_layer<32, 16><<<rblocks, 256, 0, stream>>>(
      rp, cv, out + 128, (const float*)d_in[12], (const float*)d_in[13],
      (const float*)d_in[14], (const float*)d_in[15], out + 160, n);

  k_norm<<<rblocks, 256, 0, stream>>>(out, n);
}

// Round 8
// 1857.092 us; speedup vs baseline: 1.4023x; 1.0027x over previous
//
#include <hip/hip_runtime.h>
#include <hip/hip_bf16.h>

#define LEAKY(v) ((v) >= 0.0f ? (v) : 0.01f * (v))

typedef int iv4 __attribute__((ext_vector_type(4)));
typedef unsigned short us4 __attribute__((ext_vector_type(4)));

__device__ __forceinline__ unsigned short f2bf(float v) {
  unsigned u = __float_as_uint(v);
  return (unsigned short)((u + 0x7fffu + ((u >> 16) & 1u)) >> 16);  // RNE
}
__device__ __forceinline__ float bf2f(unsigned short h) {
  return __uint_as_float((unsigned)h << 16);
}

// ---------------------------------------------------------------------------
// k_init: ego -> out cols [0,64) (f32) and -> xh (bf16 gather table).
// ---------------------------------------------------------------------------
__global__ void k_init(const float* __restrict__ ego, float* __restrict__ out,
                       unsigned short* __restrict__ xh, int n) {
  int tid = blockIdx.x * blockDim.x + threadIdx.x;
  int total = n * 16;
  int stride = gridDim.x * blockDim.x;
  for (int t = tid; t < total; t += stride) {
    int r = t >> 4, c = (t & 15) * 4;
    float4 v = *(const float4*)(ego + (size_t)r * 64 + c);
    *(float4*)(out + (size_t)r * 176 + c) = v;
    us4 h;
    h.x = f2bf(v.x); h.y = f2bf(v.y); h.z = f2bf(v.z); h.w = f2bf(v.w);
    *(us4*)(xh + (size_t)r * 64 + c) = h;
  }
}

// ---------------------------------------------------------------------------
// k_pack: refresh xh from out cols [col0, col0+DOUT) (unnormalized layer out).
// ---------------------------------------------------------------------------
template <int DOUT>
__global__ void k_pack(const float* __restrict__ src, unsigned short* __restrict__ xh,
                       int n) {
  int tid = blockIdx.x * blockDim.x + threadIdx.x;
  int total = n * (DOUT / 4);
  int stride = gridDim.x * blockDim.x;
  constexpr int Q = DOUT / 4;
  for (int t = tid; t < total; t += stride) {
    int r = t / Q, c = (t - r * Q) * 4;
    float4 v = *(const float4*)(src + (size_t)r * 176 + c);
    us4 h;
    h.x = f2bf(v.x); h.y = f2bf(v.y); h.z = f2bf(v.z); h.w = f2bf(v.w);
    *(us4*)(xh + (size_t)r * 64 + c) = h;
  }
}

// ---------------------------------------------------------------------------
// CSR build: histogram -> single-block scan -> scatter (col,val as int2)
// ---------------------------------------------------------------------------
__global__ void k_count(const int* __restrict__ erow, int* __restrict__ cnt, int E) {
  int tid = blockIdx.x * blockDim.x + threadIdx.x;
  int stride = gridDim.x * blockDim.x;
  for (int e = tid; e < E; e += stride) atomicAdd(&cnt[erow[e]], 1);
}

__global__ void __launch_bounds__(1024) k_scan(const int* __restrict__ cnt,
                                               int* __restrict__ rp, int n) {
  __shared__ int ssum[1024];
  int t = threadIdx.x;
  int chunk = (n + 1023) >> 10;
  int beg = t * chunk;
  int end = min(beg + chunk, n);
  int s = 0;
  for (int i = beg; i < end; ++i) s += cnt[i];
  ssum[t] = s;
  __syncthreads();
  for (int off = 1; off < 1024; off <<= 1) {
    int v = (t >= off) ? ssum[t - off] : 0;
    __syncthreads();
    ssum[t] += v;
    __syncthreads();
  }
  int excl = (t == 0) ? 0 : ssum[t - 1];
  for (int i = beg; i < end; ++i) {
    rp[i] = excl;
    excl += cnt[i];
  }
  if (t == 1023) rp[n] = excl;
}

__global__ void k_scatter(const int* __restrict__ erow, const int* __restrict__ ecol,
                          const float* __restrict__ ev, int* cur,
                          int2* __restrict__ cv, int E) {
  int tid = blockIdx.x * blockDim.x + threadIdx.x;
  int stride = gridDim.x * blockDim.x;
  for (int e = tid; e < E; e += stride) {
    int r = erow[e];
    int pos = atomicAdd(&cur[r], 1);
    int2 p;
    p.x = ecol[e];
    p.y = __float_as_int(ev[e]);
    cv[pos] = p;
  }
}

// ---------------------------------------------------------------------------
// k_layer: fused SpMM (CSR gather from bf16 xh) + transform. One wave per row.
//   side = sum val_e * bf16(x)[col_e]  (registers, lane = feature)
//   xn = leaky((x+side)@W1+b1) + leaky((x*side)@W2+b2)  -> outp (UNnormalized)
// Own-row xv read in f32 from xin (= out + col0_in). W1/W2 packed bf16-pair
// per u32 LDS word. launch_bounds(256,8) caps VGPRs for occupancy.
// ---------------------------------------------------------------------------
template <int DIN, int DOUT>
__global__ void __launch_bounds__(256, 8) k_layer(
    const int* __restrict__ rp, const int2* __restrict__ cv,
    const unsigned short* __restrict__ xh, const float* xin,
    const float* __restrict__ W1, const float* __restrict__ b1,
    const float* __restrict__ W2, const float* __restrict__ b2,
    float* outp, int n) {
  __shared__ unsigned sWp[DIN * DOUT + 64];  // lo16 = bf16(W1), hi16 = bf16(W2)
  __shared__ float sb[128];
  for (int i = threadIdx.x; i < DIN * DOUT + 64; i += blockDim.x) {
    float w1 = (i < DIN * DOUT) ? W1[i] : 0.0f;
    float w2 = (i < DIN * DOUT) ? W2[i] : 0.0f;
    unsigned u1 = __float_as_uint(w1), u2 = __float_as_uint(w2);
    unsigned r1 = (u1 + 0x7fffu + ((u1 >> 16) & 1u)) >> 16;
    unsigned r2 = (u2 + 0x7fffu + ((u2 >> 16) & 1u)) & 0xffff0000u;
    sWp[i] = r1 | r2;
  }
  if (threadIdx.x < 64) {
    int i = threadIdx.x;
    sb[i] = (i < DOUT) ? b1[i] : 0.0f;
    sb[64 + i] = (i < DOUT) ? b2[i] : 0.0f;
  }
  __syncthreads();

  int row = (int)((blockIdx.x * (unsigned)blockDim.x + threadIdx.x) >> 6);
  int lane = threadIdx.x & 63;
  if (row >= n) return;

  int f = lane & (DIN - 1);
  int beg = rp[row], end = rp[row + 1];

  float xv = (lane < DIN) ? xin[(size_t)row * 176 + lane] : 0.0f;

  float acc = 0.0f;
  int e = beg;
  if ((e & 1) && e < end) {
    int2 q = cv[e];
    acc = fmaf(__int_as_float(q.y), bf2f(xh[(size_t)q.x * 64 + f]), acc);
    ++e;
  }
  for (; e + 4 <= end; e += 4) {
    iv4 a = *(const iv4*)(cv + e);
    iv4 b = *(const iv4*)(cv + e + 2);
    float g0 = bf2f(xh[(size_t)a.x * 64 + f]);
    float g1 = bf2f(xh[(size_t)a.z * 64 + f]);
    float g2 = bf2f(xh[(size_t)b.x * 64 + f]);
    float g3 = bf2f(xh[(size_t)b.z * 64 + f]);
    acc = fmaf(__int_as_float(a.y), g0, acc);
    acc = fmaf(__int_as_float(a.w), g1, acc);
    acc = fmaf(__int_as_float(b.y), g2, acc);
    acc = fmaf(__int_as_float(b.w), g3, acc);
  }
  for (; e + 2 <= end; e += 2) {
    iv4 a = *(const iv4*)(cv + e);
    float g0 = bf2f(xh[(size_t)a.x * 64 + f]);
    float g1 = bf2f(xh[(size_t)a.z * 64 + f]);
    acc = fmaf(__int_as_float(a.y), g0, acc);
    acc = fmaf(__int_as_float(a.w), g1, acc);
  }
  if (e < end) {
    int2 q = cv[e];
    acc = fmaf(__int_as_float(q.y), bf2f(xh[(size_t)q.x * 64 + f]), acc);
  }

  float a_ = xv + acc;
  float m_ = xv * acc;

  float acc1 = sb[lane], acc2 = sb[64 + lane];
#pragma unroll 8
  for (int k = 0; k < DIN; ++k) {
    float ak = __shfl(a_, k), mk = __shfl(m_, k);
    unsigned w = sWp[k * DOUT + lane];
    acc1 = fmaf(ak, __uint_as_float(w << 16), acc1);
    acc2 = fmaf(mk, __uint_as_float(w & 0xffff0000u), acc2);
  }
  float xn = LEAKY(acc1) + LEAKY(acc2);
  if (lane < DOUT) outp[(size_t)row * 176 + lane] = xn;
}

// ---------------------------------------------------------------------------
// k_norm: L2-normalize cols [64,128), [128,160), [160,176) in place.
// ---------------------------------------------------------------------------
__global__ void __launch_bounds__(256) k_norm(float* out, int n) {
  int row = (int)((blockIdx.x * (unsigned)blockDim.x + threadIdx.x) >> 6);
  int lane = threadIdx.x & 63;
  if (row >= n) return;
  float* r = out + (size_t)row * 176;
  float a = r[64 + lane];
  float b = (lane < 48) ? r[128 + lane] : 0.0f;
  float sa = a * a;
  float sb_ = (lane < 32) ? b * b : 0.0f;
  float sc = (lane >= 32 && lane < 48) ? b * b : 0.0f;
#pragma unroll
  for (int off = 32; off; off >>= 1) {
    sa += __shfl_xor(sa, off);
    sb_ += __shfl_xor(sb_, off);
    sc += __shfl_xor(sc, off);
  }
  float ia = 1.0f / fmaxf(sqrtf(sa), 1e-12f);
  float ib = 1.0f / fmaxf(sqrtf(sb_), 1e-12f);
  float ic = 1.0f / fmaxf(sqrtf(sc), 1e-12f);
  r[64 + lane] = a * ia;
  if (lane < 48) r[128 + lane] = b * ((lane < 32) ? ib : ic);
}

// ---------------------------------------------------------------------------
extern "C" void kernel_launch(void* const* d_in, const int* in_sizes, int n_in,
                              void* d_out, int out_size, void* d_ws, size_t ws_size,
                              hipStream_t stream) {
  const float* ego = (const float*)d_in[0];
  const int* erow = (const int*)d_in[1];
  const int* ecol = (const int*)d_in[2];
  const float* ev = (const float*)d_in[3];
  const int n = in_sizes[0] / 64;  // 160000
  const int E = in_sizes[1];       // 5120000

  float* out = (float*)d_out;  // [n, 176] f32

  // ws layout: xh[n*64] bf16 (20.5 MB) | cv[E] int2 (41 MB) | rp | cnt | cur
  // total ~63.9 MB (proven budget is >= 82 MB)
  unsigned short* xh = (unsigned short*)d_ws;
  int2* cv = (int2*)(xh + (size_t)n * 64);
  int* rp = (int*)(cv + E);
  int* cnt = rp + n + 1;
  int* cur = cnt + n;

  const int rblocks = (n + 3) / 4;  // one wave per row, 4 waves/block

  k_init<<<2048, 256, 0, stream>>>(ego, out, xh, n);
  hipMemsetAsync(cnt, 0, (size_t)n * sizeof(int), stream);
  k_count<<<2048, 256, 0, stream>>>(erow, cnt, E);
  k_scan<<<1, 1024, 0, stream>>>(cnt, rp, n);
  hipMemcpyAsync(cur, rp, (size_t)n * sizeof(int), hipMemcpyDeviceToDevice, stream);
  k_scatter<<<2048, 256, 0, stream>>>(erow, ecol, ev, cur, cv, E);

  k_layer<64, 64><<<rblocks, 256, 0, stream>>>(
      rp, cv, xh, out, (const float*)d_in[4], (const float*)d_in[5],
      (const float*)d_in[6], (const float*)d_in[7], out + 64, n);
  k_pack<64><<<1024, 256, 0, stream>>>(out + 64, xh, n);
  k_layer<64, 32><<<rblocks, 256, 0, stream>>>(
      rp, cv, xh, out + 64, (const float*)d_in[8], (const float*)d_in[9],
      (const float*)d_in[10], (const float*)d_in[11], out + 128, n);
  k_pack<32><<<1024, 256, 0, stream>>>(out + 128, xh, n);
  k_layer<32, 16><<<rblocks, 256, 0, stream>>>(
      rp, cv, xh, out + 128, (const float*)d_in[12], (const float*)d_in[13],
      (const float*)d_in[14], (const float*)d_in[15], out + 160, n);

  k_norm<<<rblocks, 256, 0, stream>>>(out, n);
}

// Round 9
// 1276.976 us; speedup vs baseline: 2.0393x; 1.4543x over previous
//
#include <hip/hip_runtime.h>
#include <hip/hip_bf16.h>

#define LEAKY(v) ((v) >= 0.0f ? (v) : 0.01f * (v))

typedef int iv4 __attribute__((ext_vector_type(4)));

constexpr int SH = 9;        // rows per bucket = 512
constexpr int RPB = 1 << SH; // 512
constexpr int NBMAX = 320;   // max buckets (n <= 163840)
constexpr int CHUNK = 6144;  // edges per phase-1 block

// ---------------------------------------------------------------------------
// k_init: ego -> out cols [0,64) (raw; also serves as layer-0 input).
// ---------------------------------------------------------------------------
__global__ void k_init(const float* __restrict__ ego, float* __restrict__ out, int n) {
  int tid = blockIdx.x * blockDim.x + threadIdx.x;
  int total = n * 16;
  int stride = gridDim.x * blockDim.x;
  for (int t = tid; t < total; t += stride) {
    int r = t >> 4, c = (t & 15) * 4;
    float4 v = *(const float4*)(ego + (size_t)r * 64 + c);
    *(float4*)(out + (size_t)r * 176 + c) = v;
  }
}

// ---------------------------------------------------------------------------
// k_hist: bucket (row>>SH) histogram, LDS-staged to keep global atomics few.
// ---------------------------------------------------------------------------
__global__ void __launch_bounds__(256) k_hist(const int* __restrict__ erow,
                                              int* __restrict__ bcnt, int E, int nb) {
  __shared__ int h[NBMAX];
  for (int i = threadIdx.x; i < NBMAX; i += 256) h[i] = 0;
  __syncthreads();
  int tid = blockIdx.x * blockDim.x + threadIdx.x;
  int stride = gridDim.x * blockDim.x;
  for (int e = tid; e < E; e += stride) atomicAdd(&h[erow[e] >> SH], 1);
  __syncthreads();
  for (int b = threadIdx.x; b < nb; b += 256)
    if (h[b]) atomicAdd(&bcnt[b], h[b]);
}

// ---------------------------------------------------------------------------
// k_scanb: one wave: boff = exclusive scan of bcnt; bcur = boff; rp[n] = E.
// ---------------------------------------------------------------------------
__global__ void k_scanb(const int* __restrict__ bcnt, int* __restrict__ boff,
                        int* __restrict__ bcur, int* __restrict__ rp,
                        int nb, int n, int E) {
  int l = threadIdx.x;  // 64 threads
  constexpr int PB = NBMAX / 64;  // 5
  int local[PB];
  int s = 0;
  int base = l * PB;
  for (int j = 0; j < PB; ++j) {
    int b = base + j;
    int c = (b < nb) ? bcnt[b] : 0;
    local[j] = c;
    s += c;
  }
  int incl = s;
  for (int d = 1; d < 64; d <<= 1) {
    int v = __shfl_up(incl, d);
    if (l >= d) incl += v;
  }
  int ex = incl - s;
  for (int j = 0; j < PB; ++j) {
    int b = base + j;
    if (b <= nb) { boff[b] = ex; bcur[b] = ex; }
    ex += local[j];
  }
  if (l == 63) boff[nb] = incl;  // same value when covered above; safe
  if (l == 0) rp[n] = E;
}

// ---------------------------------------------------------------------------
// k_bucket (phase 1): per-block LDS counting-sort of a 6144-edge chunk by
// bucket; reserve per-bucket global slices; write bucket-contiguous runs.
// Entry: (localrow<<18 | col, valbits) — n < 2^18, localrow < 2^SH.
// ---------------------------------------------------------------------------
__global__ void __launch_bounds__(256) k_bucket(
    const int* __restrict__ erow, const int* __restrict__ ecol,
    const float* __restrict__ ev, int* __restrict__ bcur,
    int2* __restrict__ bkt, int E, int nb) {
  __shared__ int hist[NBMAX];
  __shared__ int excl[NBMAX + 1];
  __shared__ int curl[NBMAX];
  __shared__ int gbase[NBMAX];
  __shared__ int2 skv[CHUNK];
  int base = blockIdx.x * CHUNK;
  int cnt = min(CHUNK, E - base);

  for (int i = threadIdx.x; i < NBMAX; i += 256) hist[i] = 0;
  __syncthreads();
  for (int i = threadIdx.x; i < cnt; i += 256)
    atomicAdd(&hist[erow[base + i] >> SH], 1);
  __syncthreads();

  // wave-0 exclusive scan over NBMAX buckets
  if (threadIdx.x < 64) {
    int l = threadIdx.x;
    constexpr int PB = NBMAX / 64;
    int lsum[PB];
    int s = 0;
    for (int j = 0; j < PB; ++j) { lsum[j] = hist[l * PB + j]; s += lsum[j]; }
    int incl = s;
    for (int d = 1; d < 64; d <<= 1) {
      int v = __shfl_up(incl, d);
      if (l >= d) incl += v;
    }
    int ex = incl - s;
    for (int j = 0; j < PB; ++j) { excl[l * PB + j] = ex; ex += lsum[j]; }
    if (l == 63) excl[NBMAX] = incl;
  }
  __syncthreads();

  for (int b = threadIdx.x; b < nb; b += 256) {
    curl[b] = 0;
    int c = hist[b];
    if (c) gbase[b] = atomicAdd(&bcur[b], c);
  }
  __syncthreads();

  for (int i = threadIdx.x; i < cnt; i += 256) {
    int r = erow[base + i];
    int b = r >> SH;
    int lr = r & (RPB - 1);
    int slot = excl[b] + atomicAdd(&curl[b], 1);
    int2 p;
    p.x = (lr << 18) | ecol[base + i];
    p.y = __float_as_int(ev[base + i]);
    skv[slot] = p;
  }
  __syncthreads();

  for (int s = threadIdx.x; s < cnt; s += 256) {
    int lo = 0, hi = nb;  // find b: excl[b] <= s < excl[b+1]
    while (hi - lo > 1) {
      int mid = (lo + hi) >> 1;
      if (excl[mid] <= s) lo = mid; else hi = mid;
    }
    bkt[gbase[lo] + (s - excl[lo])] = skv[s];
  }
}

// ---------------------------------------------------------------------------
// k_bsort (phase 2): one block per bucket; counting-sort by exact local row
// inside the bucket's (L2-resident) window; write final cv + rp.
// ---------------------------------------------------------------------------
__global__ void __launch_bounds__(512) k_bsort(
    const int* __restrict__ boff, const int2* __restrict__ bkt,
    int2* __restrict__ cv, int* __restrict__ rp, int n) {
  __shared__ int cnt[RPB];
  __shared__ int sc[RPB];
  __shared__ int exs[RPB];
  __shared__ int cur[RPB];
  int b = blockIdx.x;
  int off = boff[b];
  int m = boff[b + 1] - off;
  int t = threadIdx.x;

  cnt[t] = 0;
  __syncthreads();
  for (int i = t; i < m; i += 512) atomicAdd(&cnt[bkt[off + i].x >> 18], 1);
  __syncthreads();
  sc[t] = cnt[t];
  __syncthreads();
  for (int o = 1; o < RPB; o <<= 1) {
    int v = (t >= o) ? sc[t - o] : 0;
    __syncthreads();
    sc[t] += v;
    __syncthreads();
  }
  int ex = sc[t] - cnt[t];
  exs[t] = ex;
  cur[t] = 0;
  int row = (b << SH) + t;
  if (row < n) rp[row] = off + ex;
  __syncthreads();
  for (int i = t; i < m; i += 512) {
    int2 p = bkt[off + i];
    int lr = p.x >> 18;
    int pos = exs[lr] + atomicAdd(&cur[lr], 1);
    int2 q;
    q.x = p.x & 0x3FFFF;
    q.y = p.y;
    cv[off + pos] = q;
  }
}

// ---------------------------------------------------------------------------
// k_layer: fused SpMM (CSR gather) + transform. One wave per row.
// launch_bounds(256,8) caps VGPRs; W1/W2 packed bf16-pair per u32 LDS word.
//   side = sum val_e * xin[col_e]; xn = leaky((x+s)W1+b1)+leaky((x*s)W2+b2)
// xin/outp alias out (disjoint column ranges) -> no __restrict__.
// ---------------------------------------------------------------------------
template <int DIN, int DOUT>
__global__ void __launch_bounds__(256, 8) k_layer(
    const int* __restrict__ rp, const int2* __restrict__ cv,
    const float* xin,
    const float* __restrict__ W1, const float* __restrict__ b1,
    const float* __restrict__ W2, const float* __restrict__ b2,
    float* outp, int n) {
  __shared__ unsigned sWp[DIN * DOUT + 64];  // lo16 = bf16(W1), hi16 = bf16(W2)
  __shared__ float sb[128];
  for (int i = threadIdx.x; i < DIN * DOUT + 64; i += blockDim.x) {
    float w1 = (i < DIN * DOUT) ? W1[i] : 0.0f;
    float w2 = (i < DIN * DOUT) ? W2[i] : 0.0f;
    unsigned u1 = __float_as_uint(w1), u2 = __float_as_uint(w2);
    unsigned r1 = (u1 + 0x7fffu + ((u1 >> 16) & 1u)) >> 16;
    unsigned r2 = (u2 + 0x7fffu + ((u2 >> 16) & 1u)) & 0xffff0000u;
    sWp[i] = r1 | r2;
  }
  if (threadIdx.x < 64) {
    int i = threadIdx.x;
    sb[i] = (i < DOUT) ? b1[i] : 0.0f;
    sb[64 + i] = (i < DOUT) ? b2[i] : 0.0f;
  }
  __syncthreads();

  int row = (int)((blockIdx.x * (unsigned)blockDim.x + threadIdx.x) >> 6);
  int lane = threadIdx.x & 63;
  if (row >= n) return;

  int f = lane & (DIN - 1);
  int beg = rp[row], end = rp[row + 1];

  float xv = (lane < DIN) ? xin[(size_t)row * 176 + lane] : 0.0f;

  float acc = 0.0f;
  int e = beg;
  if ((e & 1) && e < end) {
    int2 q = cv[e];
    acc = fmaf(__int_as_float(q.y), xin[(size_t)q.x * 176 + f], acc);
    ++e;
  }
  for (; e + 4 <= end; e += 4) {
    iv4 a = *(const iv4*)(cv + e);
    iv4 b = *(const iv4*)(cv + e + 2);
    float g0 = xin[(size_t)a.x * 176 + f];
    float g1 = xin[(size_t)a.z * 176 + f];
    float g2 = xin[(size_t)b.x * 176 + f];
    float g3 = xin[(size_t)b.z * 176 + f];
    acc = fmaf(__int_as_float(a.y), g0, acc);
    acc = fmaf(__int_as_float(a.w), g1, acc);
    acc = fmaf(__int_as_float(b.y), g2, acc);
    acc = fmaf(__int_as_float(b.w), g3, acc);
  }
  for (; e + 2 <= end; e += 2) {
    iv4 a = *(const iv4*)(cv + e);
    float g0 = xin[(size_t)a.x * 176 + f];
    float g1 = xin[(size_t)a.z * 176 + f];
    acc = fmaf(__int_as_float(a.y), g0, acc);
    acc = fmaf(__int_as_float(a.w), g1, acc);
  }
  if (e < end) {
    int2 q = cv[e];
    acc = fmaf(__int_as_float(q.y), xin[(size_t)q.x * 176 + f], acc);
  }

  float a_ = xv + acc;
  float m_ = xv * acc;

  float acc1 = sb[lane], acc2 = sb[64 + lane];
#pragma unroll 8
  for (int k = 0; k < DIN; ++k) {
    float ak = __shfl(a_, k), mk = __shfl(m_, k);
    unsigned w = sWp[k * DOUT + lane];
    acc1 = fmaf(ak, __uint_as_float(w << 16), acc1);
    acc2 = fmaf(mk, __uint_as_float(w & 0xffff0000u), acc2);
  }
  float xn = LEAKY(acc1) + LEAKY(acc2);
  if (lane < DOUT) outp[(size_t)row * 176 + lane] = xn;
}

// ---------------------------------------------------------------------------
// k_norm: L2-normalize cols [64,128), [128,160), [160,176) in place.
// ---------------------------------------------------------------------------
__global__ void __launch_bounds__(256) k_norm(float* out, int n) {
  int row = (int)((blockIdx.x * (unsigned)blockDim.x + threadIdx.x) >> 6);
  int lane = threadIdx.x & 63;
  if (row >= n) return;
  float* r = out + (size_t)row * 176;
  float a = r[64 + lane];
  float b = (lane < 48) ? r[128 + lane] : 0.0f;
  float sa = a * a;
  float sb_ = (lane < 32) ? b * b : 0.0f;
  float sc = (lane >= 32 && lane < 48) ? b * b : 0.0f;
#pragma unroll
  for (int off = 32; off; off >>= 1) {
    sa += __shfl_xor(sa, off);
    sb_ += __shfl_xor(sb_, off);
    sc += __shfl_xor(sc, off);
  }
  float ia = 1.0f / fmaxf(sqrtf(sa), 1e-12f);
  float ib = 1.0f / fmaxf(sqrtf(sb_), 1e-12f);
  float ic = 1.0f / fmaxf(sqrtf(sc), 1e-12f);
  r[64 + lane] = a * ia;
  if (lane < 48) r[128 + lane] = b * ((lane < 32) ? ib : ic);
}

// ---------------------------------------------------------------------------
extern "C" void kernel_launch(void* const* d_in, const int* in_sizes, int n_in,
                              void* d_out, int out_size, void* d_ws, size_t ws_size,
                              hipStream_t stream) {
  const float* ego = (const float*)d_in[0];
  const int* erow = (const int*)d_in[1];
  const int* ecol = (const int*)d_in[2];
  const float* ev = (const float*)d_in[3];
  const int n = in_sizes[0] / 64;  // 160000
  const int E = in_sizes[1];       // 5120000
  const int nb = (n + RPB - 1) >> SH;  // 313

  float* out = (float*)d_out;  // [n, 176] f32

  // ws: bkt[E] | cv[E] | rp[n+1] | bcnt[NBMAX] | boff[NBMAX+1] | bcur[NBMAX]
  // total ~82.7 MB (proven budget >= 83.9 MB)
  int2* bkt = (int2*)d_ws;
  int2* cv = bkt + E;
  int* rp = (int*)(cv + E);
  int* bcnt = rp + n + 1;
  int* boff = bcnt + NBMAX;
  int* bcur = boff + NBMAX + 1;

  const int rblocks = (n + 3) / 4;  // one wave per row, 4 waves/block

  k_init<<<2048, 256, 0, stream>>>(ego, out, n);
  hipMemsetAsync(bcnt, 0, NBMAX * sizeof(int), stream);
  k_hist<<<1024, 256, 0, stream>>>(erow, bcnt, E, nb);
  k_scanb<<<1, 64, 0, stream>>>(bcnt, boff, bcur, rp, nb, n, E);
  k_bucket<<<(E + CHUNK - 1) / CHUNK, 256, 0, stream>>>(erow, ecol, ev, bcur, bkt, E, nb);
  k_bsort<<<nb, 512, 0, stream>>>(boff, bkt, cv, rp, n);

  k_layer<64, 64><<<rblocks, 256, 0, stream>>>(
      rp, cv, out, (const float*)d_in[4], (const float*)d_in[5],
      (const float*)d_in[6], (const float*)d_in[7], out + 64, n);
  k_layer<64, 32><<<rblocks, 256, 0, stream>>>(
      rp, cv, out + 64, (const float*)d_in[8], (const float*)d_in[9],
      (const float*)d_in[10], (const float*)d_in[11], out + 128, n);
  k_layer<32, 16><<<rblocks, 256, 0, stream>>>(
      rp, cv, out + 128, (const float*)d_in[12], (const float*)d_in[13],
      (const float*)d_in[14], (const float*)d_in[15], out + 160, n);

  k_norm<<<rblocks, 256, 0, stream>>>(out, n);
}